// Round 2
// baseline (179.208 us; speedup 1.0000x reference)
//
#include <hip/hip_runtime.h>
#include <hip/hip_bf16.h>
#include <math.h>

#define NP 1024
#define R 32
#define C 16
#define GAMMA (32.0f/3.5f)
#define DC (3.5f/31.0f)

typedef __attribute__((ext_vector_type(8))) short bf16x8;
typedef __attribute__((ext_vector_type(4))) float f32x4;

__device__ __forceinline__ short tobf(float x){
    __hip_bfloat16 h = __float2bfloat16(x);
    return __builtin_bit_cast(short, h);
}
__device__ __forceinline__ float frombf(short s){
    __hip_bfloat16 h = __builtin_bit_cast(__hip_bfloat16, s);
    return __bfloat162float(h);
}
__device__ __forceinline__ unsigned pack2bf(float a, float b){
    const unsigned lo = (unsigned short)tobf(a);
    const unsigned hi = (unsigned short)tobf(b);
    return lo | (hi << 16);
}
__device__ __forceinline__ float eluf(float x){ return x > 0.f ? x : expm1f(x); }

__device__ __forceinline__ f32x4 mfma16(bf16x8 a, bf16x8 b, f32x4 c){
    return __builtin_amdgcn_mfma_f32_16x16x32_bf16(a, b, c, 0, 0, 0);
}

// B-operand fragment: element jj = src[(q*8+jj)*STRIDE + n]. bf16 hi+lo split
// keeps weight rounding at ~fp32 level (2 MFMAs per GEMM).
template<int STRIDE>
__device__ __forceinline__ void load_bfrag(const float* __restrict__ src, int q, int n,
                                           bf16x8& hi, bf16x8& lo){
    #pragma unroll
    for (int jj = 0; jj < 8; jj++){
        const float w = src[(q*8+jj)*STRIDE + n];
        const short h = tobf(w);
        hi[jj] = h;
        lo[jj] = tobf(w - frombf(h));
    }
}

// ---------------------------------------------------------------------------
// Kernel A: layer1 (barrier-free MFMA K-loop) fused with the per-point SI
// transform (was k_layer1 + k_point1). Block 'a' keeps its own out0/out1 in
// LDS (sO) and writes x0g/x1s directly — no out0/out1 global round-trip.
// Block 0 also zeroes the pooled accumulator + completion counter for kernel
// B (kernel boundary orders these plain stores before B's atomics).
// NOTE: no grid.sync anywhere — cooperative launch + graph capture raced in
// round 1; the single true grid-wide dependency uses the kernel boundary.
// ---------------------------------------------------------------------------
__global__ __launch_bounds__(256) void k_l1p(
    const float* __restrict__ points,
    const float* __restrict__ W1, const float* __restrict__ B1,
    const float* __restrict__ W2, const float* __restrict__ B2,
    const float* __restrict__ si0w, const float* __restrict__ si0b,
    const float* __restrict__ si1w, const float* __restrict__ nlb,
    float* __restrict__ x0g, float* __restrict__ x1s,
    float* __restrict__ partial, unsigned* __restrict__ counter)
{
    __shared__ float sS0[4][32];
    __shared__ float sT[4][32][3];
    __shared__ float sUp[4][3];
    __shared__ float sO[4];

    const int tid  = threadIdx.x;
    const int lane = tid & 63;
    const int wv   = tid >> 6;
    const int l16  = lane & 15;
    const int q    = lane >> 4;
    const int a    = blockIdx.x;
    const float pax = points[a*3+0], pay = points[a*3+1], paz = points[a*3+2];

    bf16x8 w1hi[2][2], w1lo[2][2];
    float  b1v[2][2];
    #pragma unroll
    for (int fi = 0; fi < 2; fi++)
        #pragma unroll
        for (int nt = 0; nt < 2; nt++){
            load_bfrag<R>(W1 + fi*R*R, q, nt*16 + l16, w1hi[fi][nt], w1lo[fi][nt]);
            b1v[fi][nt] = B1[fi*R + nt*16 + l16];
        }

    float s0a[2] = {0.f, 0.f};
    float T[2][3] = {};
    float upx = 0.f, upy = 0.f, upz = 0.f;

    for (int bt = 0; bt < 16; bt++){
        const int bA = bt*64 + wv*16 + l16;
        const float rx = pax - points[bA*3+0];
        const float ry = pay - points[bA*3+1];
        const float rz = paz - points[bA*3+2];
        const float ss = rx*rx + ry*ry + rz*rz;
        const float dij = sqrtf(ss);
        const float inv = 1.0f / sqrtf(fmaxf(ss, 1e-8f));
        const float ux = rx*inv, uy = ry*inv, uz = rz*inv;  // ==0 on diagonal
        upx += ux; upy += uy; upz += uz;                    // 4x overcount, /4 later

        bf16x8 afrag;
        #pragma unroll
        for (int jj = 0; jj < 8; jj++){
            const float t = dij - (float)(q*8+jj)*DC;
            afrag[jj] = tobf(__expf(-GAMMA*t*t));
        }

        float uxr[4], uyr[4], uzr[4];
        #pragma unroll
        for (int r4 = 0; r4 < 4; r4++){
            const int sl = q*4 + r4;
            uxr[r4] = __shfl(ux, sl, 16);
            uyr[r4] = __shfl(uy, sl, 16);
            uzr[r4] = __shfl(uz, sl, 16);
        }

        #pragma unroll
        for (int nt = 0; nt < 2; nt++){
            f32x4 c = {b1v[0][nt], b1v[0][nt], b1v[0][nt], b1v[0][nt]};
            c = mfma16(afrag, w1hi[0][nt], c);
            c = mfma16(afrag, w1lo[0][nt], c);
            s0a[nt] += fmaxf(c[0],0.f)+fmaxf(c[1],0.f)+fmaxf(c[2],0.f)+fmaxf(c[3],0.f);
        }
        #pragma unroll
        for (int nt = 0; nt < 2; nt++){
            f32x4 c = {b1v[1][nt], b1v[1][nt], b1v[1][nt], b1v[1][nt]};
            c = mfma16(afrag, w1hi[1][nt], c);
            c = mfma16(afrag, w1lo[1][nt], c);
            #pragma unroll
            for (int r4 = 0; r4 < 4; r4++){
                const float h = fmaxf(c[r4], 0.f);
                T[nt][0] = fmaf(h, uxr[r4], T[nt][0]);
                T[nt][1] = fmaf(h, uyr[r4], T[nt][1]);
                T[nt][2] = fmaf(h, uzr[r4], T[nt][2]);
            }
        }
    }

    // cross-quad reduce (rows live in quads)
    #pragma unroll
    for (int nt = 0; nt < 2; nt++){
        s0a[nt] += __shfl_down(s0a[nt], 32, 64);
        s0a[nt] += __shfl_down(s0a[nt], 16, 64);
        #pragma unroll
        for (int i = 0; i < 3; i++){
            T[nt][i] += __shfl_down(T[nt][i], 32, 64);
            T[nt][i] += __shfl_down(T[nt][i], 16, 64);
        }
    }
    #pragma unroll
    for (int off = 32; off > 0; off >>= 1){
        upx += __shfl_down(upx, off, 64);
        upy += __shfl_down(upy, off, 64);
        upz += __shfl_down(upz, off, 64);
    }
    if (lane < 16){
        sS0[wv][lane]      = s0a[0];
        sS0[wv][16 + lane] = s0a[1];
        #pragma unroll
        for (int i = 0; i < 3; i++){
            sT[wv][lane][i]      = T[0][i];
            sT[wv][16 + lane][i] = T[1][i];
        }
    }
    if (lane == 0){ sUp[wv][0] = upx; sUp[wv][1] = upy; sUp[wv][2] = upz; }
    __syncthreads();
    if (tid == 0){
        float o0 = 0.f;
        for (int j = 0; j < R; j++){
            const float S = sS0[0][j] + sS0[1][j] + sS0[2][j] + sS0[3][j];
            o0 = fmaf(S, W2[j], o0);
        }
        sO[0] = o0 + (float)NP * B2[0];
        for (int i = 0; i < 3; i++){
            float t = 0.f;
            for (int j = 0; j < R; j++){
                const float Tj = sT[0][j][i] + sT[1][j][i] + sT[2][j][i] + sT[3][j][i];
                t = fmaf(Tj, W2[R + j], t);
            }
            const float Ui = 0.25f * (sUp[0][i] + sUp[1][i] + sUp[2][i] + sUp[3][i]);
            sO[1+i] = t + B2[1] * Ui;
        }
    }
    __syncthreads();
    // per-point SI transform (was k_point1): block 'a' handles its own point
    if (tid < C){
        const int g = tid;
        const float o0 = sO[0];
        const float o1x = sO[1], o1y = sO[2], o1z = sO[3];
        x0g[a*C+g] = eluf(fmaf(o0, si0w[g], si0b[g]));
        const float w = si1w[g];
        const float tx = o1x*w, ty = o1y*w, tz = o1z*w;
        const float n = sqrtf(fmaxf(tx*tx + ty*ty + tz*tz, 1e-8f));
        const float sc = eluf(n + nlb[g]) / n;
        x1s[0*NP*C + a*C+g] = tx*sc;
        x1s[1*NP*C + a*C+g] = ty*sc;
        x1s[2*NP*C + a*C+g] = tz*sc;
    }
    // reset pooled accumulator + counter for kernel B (boundary orders this)
    if (a == 0){
        if (tid < C) partial[tid*16] = 0.f;   // padded: 64 B per channel
        if (tid == 0) *counter = 0u;
    }
}

// ---------------------------------------------------------------------------
// Kernel B: layer2 (filters 0/2) fused with the per-point readout and the
// mean-pool (was k_layer2 + k_readout1 + k_readout2). Per block: c00/c10 stay
// in LDS (sC); readout ELU result is atomicAdd'ed into the padded pooled
// accumulator (device-scope, XCD-coherent). The last block to finish (atomic
// counter) performs the final 8-wide FC — no cooperative launch needed.
// ---------------------------------------------------------------------------
__global__ __launch_bounds__(256) void k_l2r(
    const float* __restrict__ points,
    const float* __restrict__ W1, const float* __restrict__ B1,
    const float* __restrict__ W2, const float* __restrict__ B2,
    const float* __restrict__ x0g, const float* __restrict__ x1s,
    const float* __restrict__ si0w, const float* __restrict__ si0b,
    const float* __restrict__ fcw, const float* __restrict__ fcb,
    float* __restrict__ partial, unsigned* __restrict__ counter,
    float* __restrict__ out)
{
    __shared__ __align__(16) short sH[4][2][16*40];   // [wave][filter][row*40]
    __shared__ float sRed[4][2][16];
    __shared__ float sC[2][16];
    __shared__ float sP[16];
    __shared__ unsigned amLast;

    const int tid  = threadIdx.x;
    const int lane = tid & 63;
    const int wv   = tid >> 6;
    const int l16  = lane & 15;
    const int q    = lane >> 4;
    const int a    = blockIdx.x;
    const float pax = points[a*3+0], pay = points[a*3+1], paz = points[a*3+2];

    bf16x8 w1hi[2][2], w1lo[2][2], w2hi[2], w2lo[2];
    float  b1v[2][2], b2v[2];
    #pragma unroll
    for (int fi = 0; fi < 2; fi++){
        const int fx = (fi == 0) ? 0 : 2;
        #pragma unroll
        for (int nt = 0; nt < 2; nt++){
            load_bfrag<R>(W1 + fx*R*R, q, 2*l16 + nt, w1hi[fi][nt], w1lo[fi][nt]);
            b1v[fi][nt] = B1[fx*R + 2*l16 + nt];
        }
        load_bfrag<C>(W2 + fx*R*C, q, l16, w2hi[fi], w2lo[fi]);
        b2v[fi] = B2[fx*C + l16];
    }

    float acc0 = 0.f, acc1 = 0.f;
    short* sH0 = sH[wv][0];
    short* sH1 = sH[wv][1];

    for (int bt = 0; bt < 16; bt++){
        const int bA = bt*64 + wv*16 + l16;
        const float rx = pax - points[bA*3+0];
        const float ry = pay - points[bA*3+1];
        const float rz = paz - points[bA*3+2];
        const float ss = rx*rx + ry*ry + rz*rz;
        const float dij = sqrtf(ss);
        const float inv = 1.0f / sqrtf(fmaxf(ss, 1e-8f));
        const float ux = rx*inv, uy = ry*inv, uz = rz*inv;  // ==0 on diagonal

        float uxr[4], uyr[4], uzr[4];
        #pragma unroll
        for (int r4 = 0; r4 < 4; r4++){
            const int sl = q*4 + r4;
            uxr[r4] = __shfl(ux, sl, 16);
            uyr[r4] = __shfl(uy, sl, 16);
            uzr[r4] = __shfl(uz, sl, 16);
        }

        // epilogue inputs: rows bE = bt*64+wv*16+q*4+r4, col f = l16
        const int rb = (bt*64 + wv*16 + q*4)*C + l16;
        float x0v[4], udv[4];
        #pragma unroll
        for (int r4 = 0; r4 < 4; r4++){
            x0v[r4] = x0g[rb + r4*C];
            const float v0 = x1s[0*NP*C + rb + r4*C];
            const float v1 = x1s[1*NP*C + rb + r4*C];
            const float v2 = x1s[2*NP*C + rb + r4*C];
            udv[r4] = uxr[r4]*v0 + uyr[r4]*v1 + uzr[r4]*v2;
        }

        bf16x8 afrag;
        #pragma unroll
        for (int jj = 0; jj < 8; jj++){
            const float t = dij - (float)(q*8+jj)*DC;
            afrag[jj] = tobf(__expf(-GAMMA*t*t));
        }

        // GEMM1 both filters -> packed bf16 H into wave-private LDS
        #pragma unroll
        for (int fi = 0; fi < 2; fi++){
            f32x4 c0 = {b1v[fi][0], b1v[fi][0], b1v[fi][0], b1v[fi][0]};
            c0 = mfma16(afrag, w1hi[fi][0], c0);
            c0 = mfma16(afrag, w1lo[fi][0], c0);
            f32x4 c1 = {b1v[fi][1], b1v[fi][1], b1v[fi][1], b1v[fi][1]};
            c1 = mfma16(afrag, w1hi[fi][1], c1);
            c1 = mfma16(afrag, w1lo[fi][1], c1);
            short* sHf = (fi == 0) ? sH0 : sH1;
            #pragma unroll
            for (int r4 = 0; r4 < 4; r4++){
                const unsigned p = pack2bf(fmaxf(c0[r4], 0.f), fmaxf(c1[r4], 0.f));
                *(unsigned*)&sHf[(q*4+r4)*40 + 2*l16] = p;   // j=2*l16 (lo), 2*l16+1 (hi)
            }
        }
        asm volatile("s_waitcnt lgkmcnt(0)" ::: "memory");   // wave-internal transpose
        #pragma unroll
        for (int fi = 0; fi < 2; fi++){
            const short* sHf = (fi == 0) ? sH0 : sH1;
            const bf16x8 hf = *(const bf16x8*)(sHf + l16*40 + q*8);
            f32x4 d = {0.f, 0.f, 0.f, 0.f};
            d = mfma16(hf, w2hi[fi], d);
            d = mfma16(hf, w2lo[fi], d);
            #pragma unroll
            for (int r4 = 0; r4 < 4; r4++){
                const float v = d[r4] + b2v[fi];
                if (fi == 0) acc0 = fmaf(v, x0v[r4], acc0);
                else         acc1 = fmaf(v, udv[r4], acc1);
            }
        }
    }

    acc0 += __shfl_down(acc0, 32, 64); acc0 += __shfl_down(acc0, 16, 64);
    acc1 += __shfl_down(acc1, 32, 64); acc1 += __shfl_down(acc1, 16, 64);
    if (lane < 16){ sRed[wv][0][lane] = acc0; sRed[wv][1][lane] = acc1; }
    __syncthreads();
    if (tid < 16){
        sC[0][tid] = sRed[0][0][tid] + sRed[1][0][tid] + sRed[2][0][tid] + sRed[3][0][tid];
        sC[1][tid] = sRed[0][1][tid] + sRed[1][1][tid] + sRed[2][1][tid] + sRed[3][1][tid];
    }
    __syncthreads();
    // per-point readout (was k_readout1) + pooled accumulation
    if (tid < C){
        const int g = tid;
        float s = si0b[g];
        #pragma unroll
        for (int f = 0; f < C; f++) s = fmaf(sC[0][f], si0w[g*2*C + f], s);
        #pragma unroll
        for (int f = 0; f < C; f++) s = fmaf(sC[1][f], si0w[g*2*C + C + f], s);
        atomicAdd(&partial[g*16], eluf(s));   // padded 64 B apart: no same-line pileup
    }
    // last-block-done: the final block performs the FC (was k_readout2)
    __syncthreads();                          // barrier drains this block's atomics
    if (tid == 0){
        __threadfence();
        const unsigned prev = atomicAdd(counter, 1u);
        amLast = (prev == NP - 1u) ? 1u : 0u;
    }
    __syncthreads();
    if (amLast){
        __threadfence();
        if (tid < C)
            sP[tid] = __hip_atomic_load(&partial[tid*16], __ATOMIC_RELAXED,
                                        __HIP_MEMORY_SCOPE_AGENT);
        __syncthreads();
        if (tid < 8){
            float s = fcb[tid];
            #pragma unroll
            for (int g = 0; g < C; g++)
                s = fmaf(sP[g] * (1.0f / (float)NP), fcw[g*8 + tid], s);
            out[tid] = s;
        }
    }
}

extern "C" void kernel_launch(void* const* d_in, const int* in_sizes, int n_in,
                              void* d_out, int out_size, void* d_ws, size_t ws_size,
                              hipStream_t stream)
{
    (void)in_sizes; (void)n_in; (void)out_size; (void)ws_size;
    const float* points   = (const float*)d_in[0];
    const float* l1_W1    = (const float*)d_in[1];
    const float* l1_B1    = (const float*)d_in[2];
    const float* l1_W2    = (const float*)d_in[3];
    const float* l1_B2    = (const float*)d_in[4];
    const float* l1_si0_w = (const float*)d_in[5];
    const float* l1_si0_b = (const float*)d_in[6];
    const float* l1_si1_w = (const float*)d_in[7];
    const float* l1_nl_b  = (const float*)d_in[8];
    const float* l2_W1    = (const float*)d_in[9];
    const float* l2_B1    = (const float*)d_in[10];
    const float* l2_W2    = (const float*)d_in[11];
    const float* l2_B2    = (const float*)d_in[12];
    const float* l2_si0_w = (const float*)d_in[13];
    const float* l2_si0_b = (const float*)d_in[14];
    // d_in[15] l2_si1_w, d_in[16] l2_nl_b: dead code in the reference readout
    const float* fc_w     = (const float*)d_in[17];
    const float* fc_b     = (const float*)d_in[18];

    float* ws       = (float*)d_ws;
    float* x0g      = ws;                    // NP*C
    float* x1s      = x0g + NP*C;            // 3*NP*C (SoA planes)
    float* partial  = x1s + 3*NP*C;          // C*16 padded floats
    unsigned* counter = (unsigned*)(partial + C*16);

    k_l1p<<<NP, 256, 0, stream>>>(points, l1_W1, l1_B1, l1_W2, l1_B2,
                                  l1_si0_w, l1_si0_b, l1_si1_w, l1_nl_b,
                                  x0g, x1s, partial, counter);
    k_l2r<<<NP, 256, 0, stream>>>(points, l2_W1, l2_B1, l2_W2, l2_B2,
                                  x0g, x1s, l2_si0_w, l2_si0_b,
                                  fc_w, fc_b, partial, counter, (float*)d_out);
}

// Round 3
// 160.472 us; speedup vs baseline: 1.1168x; 1.1168x over previous
//
#include <hip/hip_runtime.h>
#include <hip/hip_bf16.h>
#include <math.h>

#define NP 1024
#define R 32
#define C 16
#define GAMMA (32.0f/3.5f)
#define DC (3.5f/31.0f)
#define NBANK 32   // pooled-accumulator banks (each = one 64B line)

typedef __attribute__((ext_vector_type(8))) short bf16x8;
typedef __attribute__((ext_vector_type(4))) float f32x4;

__device__ __forceinline__ short tobf(float x){
    __hip_bfloat16 h = __float2bfloat16(x);
    return __builtin_bit_cast(short, h);
}
__device__ __forceinline__ float frombf(short s){
    __hip_bfloat16 h = __builtin_bit_cast(__hip_bfloat16, s);
    return __bfloat162float(h);
}
__device__ __forceinline__ unsigned pack2bf(float a, float b){
    const unsigned lo = (unsigned short)tobf(a);
    const unsigned hi = (unsigned short)tobf(b);
    return lo | (hi << 16);
}
__device__ __forceinline__ float eluf(float x){ return x > 0.f ? x : expm1f(x); }

__device__ __forceinline__ f32x4 mfma16(bf16x8 a, bf16x8 b, f32x4 c){
    return __builtin_amdgcn_mfma_f32_16x16x32_bf16(a, b, c, 0, 0, 0);
}

// B-operand fragment: element jj = src[(q*8+jj)*STRIDE + n]. bf16 hi+lo split
// keeps weight rounding at ~fp32 level (2 MFMAs per GEMM).
template<int STRIDE>
__device__ __forceinline__ void load_bfrag(const float* __restrict__ src, int q, int n,
                                           bf16x8& hi, bf16x8& lo){
    #pragma unroll
    for (int jj = 0; jj < 8; jj++){
        const float w = src[(q*8+jj)*STRIDE + n];
        const short h = tobf(w);
        hi[jj] = h;
        lo[jj] = tobf(w - frombf(h));
    }
}

// ---------------------------------------------------------------------------
// Kernel A: layer1 (barrier-free MFMA K-loop) fused with the per-point SI
// transform (was k_layer1 + k_point1). Block 'a' keeps its own out0/out1 in
// LDS (sO) and writes x0g/x1s directly. Block 0 zeroes the banked pooled
// accumulator + the two-level completion counters for kernel B (the kernel
// boundary orders these plain stores before B's atomics).
// ---------------------------------------------------------------------------
__global__ __launch_bounds__(256) void k_l1p(
    const float* __restrict__ points,
    const float* __restrict__ W1, const float* __restrict__ B1,
    const float* __restrict__ W2, const float* __restrict__ B2,
    const float* __restrict__ si0w, const float* __restrict__ si0b,
    const float* __restrict__ si1w, const float* __restrict__ nlb,
    float* __restrict__ x0g, float* __restrict__ x1s,
    float* __restrict__ partial, unsigned* __restrict__ cnt)
{
    __shared__ float sS0[4][32];
    __shared__ float sT[4][32][3];
    __shared__ float sUp[4][3];
    __shared__ float sO[4];

    const int tid  = threadIdx.x;
    const int lane = tid & 63;
    const int wv   = tid >> 6;
    const int l16  = lane & 15;
    const int q    = lane >> 4;
    const int a    = blockIdx.x;
    const float pax = points[a*3+0], pay = points[a*3+1], paz = points[a*3+2];

    bf16x8 w1hi[2][2], w1lo[2][2];
    float  b1v[2][2];
    #pragma unroll
    for (int fi = 0; fi < 2; fi++)
        #pragma unroll
        for (int nt = 0; nt < 2; nt++){
            load_bfrag<R>(W1 + fi*R*R, q, nt*16 + l16, w1hi[fi][nt], w1lo[fi][nt]);
            b1v[fi][nt] = B1[fi*R + nt*16 + l16];
        }

    float s0a[2] = {0.f, 0.f};
    float T[2][3] = {};
    float upx = 0.f, upy = 0.f, upz = 0.f;

    for (int bt = 0; bt < 16; bt++){
        const int bA = bt*64 + wv*16 + l16;
        const float rx = pax - points[bA*3+0];
        const float ry = pay - points[bA*3+1];
        const float rz = paz - points[bA*3+2];
        const float ss = rx*rx + ry*ry + rz*rz;
        const float dij = sqrtf(ss);
        const float inv = 1.0f / sqrtf(fmaxf(ss, 1e-8f));
        const float ux = rx*inv, uy = ry*inv, uz = rz*inv;  // ==0 on diagonal
        upx += ux; upy += uy; upz += uz;                    // 4x overcount, /4 later

        bf16x8 afrag;
        #pragma unroll
        for (int jj = 0; jj < 8; jj++){
            const float t = dij - (float)(q*8+jj)*DC;
            afrag[jj] = tobf(__expf(-GAMMA*t*t));
        }

        float uxr[4], uyr[4], uzr[4];
        #pragma unroll
        for (int r4 = 0; r4 < 4; r4++){
            const int sl = q*4 + r4;
            uxr[r4] = __shfl(ux, sl, 16);
            uyr[r4] = __shfl(uy, sl, 16);
            uzr[r4] = __shfl(uz, sl, 16);
        }

        #pragma unroll
        for (int nt = 0; nt < 2; nt++){
            f32x4 c = {b1v[0][nt], b1v[0][nt], b1v[0][nt], b1v[0][nt]};
            c = mfma16(afrag, w1hi[0][nt], c);
            c = mfma16(afrag, w1lo[0][nt], c);
            s0a[nt] += fmaxf(c[0],0.f)+fmaxf(c[1],0.f)+fmaxf(c[2],0.f)+fmaxf(c[3],0.f);
        }
        #pragma unroll
        for (int nt = 0; nt < 2; nt++){
            f32x4 c = {b1v[1][nt], b1v[1][nt], b1v[1][nt], b1v[1][nt]};
            c = mfma16(afrag, w1hi[1][nt], c);
            c = mfma16(afrag, w1lo[1][nt], c);
            #pragma unroll
            for (int r4 = 0; r4 < 4; r4++){
                const float h = fmaxf(c[r4], 0.f);
                T[nt][0] = fmaf(h, uxr[r4], T[nt][0]);
                T[nt][1] = fmaf(h, uyr[r4], T[nt][1]);
                T[nt][2] = fmaf(h, uzr[r4], T[nt][2]);
            }
        }
    }

    // cross-quad reduce (rows live in quads)
    #pragma unroll
    for (int nt = 0; nt < 2; nt++){
        s0a[nt] += __shfl_down(s0a[nt], 32, 64);
        s0a[nt] += __shfl_down(s0a[nt], 16, 64);
        #pragma unroll
        for (int i = 0; i < 3; i++){
            T[nt][i] += __shfl_down(T[nt][i], 32, 64);
            T[nt][i] += __shfl_down(T[nt][i], 16, 64);
        }
    }
    #pragma unroll
    for (int off = 32; off > 0; off >>= 1){
        upx += __shfl_down(upx, off, 64);
        upy += __shfl_down(upy, off, 64);
        upz += __shfl_down(upz, off, 64);
    }
    if (lane < 16){
        sS0[wv][lane]      = s0a[0];
        sS0[wv][16 + lane] = s0a[1];
        #pragma unroll
        for (int i = 0; i < 3; i++){
            sT[wv][lane][i]      = T[0][i];
            sT[wv][16 + lane][i] = T[1][i];
        }
    }
    if (lane == 0){ sUp[wv][0] = upx; sUp[wv][1] = upy; sUp[wv][2] = upz; }
    __syncthreads();
    if (tid == 0){
        float o0 = 0.f;
        for (int j = 0; j < R; j++){
            const float S = sS0[0][j] + sS0[1][j] + sS0[2][j] + sS0[3][j];
            o0 = fmaf(S, W2[j], o0);
        }
        sO[0] = o0 + (float)NP * B2[0];
        for (int i = 0; i < 3; i++){
            float t = 0.f;
            for (int j = 0; j < R; j++){
                const float Tj = sT[0][j][i] + sT[1][j][i] + sT[2][j][i] + sT[3][j][i];
                t = fmaf(Tj, W2[R + j], t);
            }
            const float Ui = 0.25f * (sUp[0][i] + sUp[1][i] + sUp[2][i] + sUp[3][i]);
            sO[1+i] = t + B2[1] * Ui;
        }
    }
    __syncthreads();
    // per-point SI transform (was k_point1): block 'a' handles its own point
    if (tid < C){
        const int g = tid;
        const float o0 = sO[0];
        const float o1x = sO[1], o1y = sO[2], o1z = sO[3];
        x0g[a*C+g] = eluf(fmaf(o0, si0w[g], si0b[g]));
        const float w = si1w[g];
        const float tx = o1x*w, ty = o1y*w, tz = o1z*w;
        const float n = sqrtf(fmaxf(tx*tx + ty*ty + tz*tz, 1e-8f));
        const float sc = eluf(n + nlb[g]) / n;
        x1s[0*NP*C + a*C+g] = tx*sc;
        x1s[1*NP*C + a*C+g] = ty*sc;
        x1s[2*NP*C + a*C+g] = tz*sc;
    }
    // reset banked pooled accumulator + counters for kernel B
    if (a == 0){
        partial[tid]       = 0.f;             // 256 of 512
        partial[256 + tid] = 0.f;             // rest
        if (tid < NBANK) cnt[tid] = __float_as_uint(0.f) * 0u;  // cnt1[32]
        if (tid < NBANK) ((unsigned*)cnt)[tid] = 0u;
        if (tid == 0) ((unsigned*)cnt)[NBANK] = 0u;             // cnt2
    }
}

// ---------------------------------------------------------------------------
// Kernel B: layer2 (filters 0/2) fused with per-point readout + mean-pool +
// final FC. Pool tail is de-serialized vs round 2:
//  - NO __threadfence (no L2 writeback storms) — all cross-block data moves
//    via device-scope atomics; __syncthreads drains vmcnt before the counter.
//  - partial is banked 32 ways (block a -> bank a&31, one 64B line each):
//    per-line atomic chain depth 1024 -> 32.
//  - two-level completion counter: cnt1[a&31] (depth 32), group-finisher
//    bumps cnt2 (depth 32). Global last block reduces banks + does the FC
//    with agent-scope loads (bypass stale local caches).
// ---------------------------------------------------------------------------
__global__ __launch_bounds__(256) void k_l2r(
    const float* __restrict__ points,
    const float* __restrict__ W1, const float* __restrict__ B1,
    const float* __restrict__ W2, const float* __restrict__ B2,
    const float* __restrict__ x0g, const float* __restrict__ x1s,
    const float* __restrict__ si0w, const float* __restrict__ si0b,
    const float* __restrict__ fcw, const float* __restrict__ fcb,
    float* __restrict__ partial, unsigned* __restrict__ cnt,
    float* __restrict__ out)
{
    __shared__ __align__(16) short sH[4][2][16*40];   // [wave][filter][row*40]
    __shared__ float sRed[4][2][16];
    __shared__ float sC[2][16];
    __shared__ float sP[16];
    __shared__ unsigned amLast;

    const int tid  = threadIdx.x;
    const int lane = tid & 63;
    const int wv   = tid >> 6;
    const int l16  = lane & 15;
    const int q    = lane >> 4;
    const int a    = blockIdx.x;
    const float pax = points[a*3+0], pay = points[a*3+1], paz = points[a*3+2];

    bf16x8 w1hi[2][2], w1lo[2][2], w2hi[2], w2lo[2];
    float  b1v[2][2], b2v[2];
    #pragma unroll
    for (int fi = 0; fi < 2; fi++){
        const int fx = (fi == 0) ? 0 : 2;
        #pragma unroll
        for (int nt = 0; nt < 2; nt++){
            load_bfrag<R>(W1 + fx*R*R, q, 2*l16 + nt, w1hi[fi][nt], w1lo[fi][nt]);
            b1v[fi][nt] = B1[fx*R + 2*l16 + nt];
        }
        load_bfrag<C>(W2 + fx*R*C, q, l16, w2hi[fi], w2lo[fi]);
        b2v[fi] = B2[fx*C + l16];
    }

    float acc0 = 0.f, acc1 = 0.f;
    short* sH0 = sH[wv][0];
    short* sH1 = sH[wv][1];

    for (int bt = 0; bt < 16; bt++){
        const int bA = bt*64 + wv*16 + l16;
        const float rx = pax - points[bA*3+0];
        const float ry = pay - points[bA*3+1];
        const float rz = paz - points[bA*3+2];
        const float ss = rx*rx + ry*ry + rz*rz;
        const float dij = sqrtf(ss);
        const float inv = 1.0f / sqrtf(fmaxf(ss, 1e-8f));
        const float ux = rx*inv, uy = ry*inv, uz = rz*inv;  // ==0 on diagonal

        float uxr[4], uyr[4], uzr[4];
        #pragma unroll
        for (int r4 = 0; r4 < 4; r4++){
            const int sl = q*4 + r4;
            uxr[r4] = __shfl(ux, sl, 16);
            uyr[r4] = __shfl(uy, sl, 16);
            uzr[r4] = __shfl(uz, sl, 16);
        }

        // epilogue inputs: rows bE = bt*64+wv*16+q*4+r4, col f = l16
        const int rb = (bt*64 + wv*16 + q*4)*C + l16;
        float x0v[4], udv[4];
        #pragma unroll
        for (int r4 = 0; r4 < 4; r4++){
            x0v[r4] = x0g[rb + r4*C];
            const float v0 = x1s[0*NP*C + rb + r4*C];
            const float v1 = x1s[1*NP*C + rb + r4*C];
            const float v2 = x1s[2*NP*C + rb + r4*C];
            udv[r4] = uxr[r4]*v0 + uyr[r4]*v1 + uzr[r4]*v2;
        }

        bf16x8 afrag;
        #pragma unroll
        for (int jj = 0; jj < 8; jj++){
            const float t = dij - (float)(q*8+jj)*DC;
            afrag[jj] = tobf(__expf(-GAMMA*t*t));
        }

        // GEMM1 both filters -> packed bf16 H into wave-private LDS
        #pragma unroll
        for (int fi = 0; fi < 2; fi++){
            f32x4 c0 = {b1v[fi][0], b1v[fi][0], b1v[fi][0], b1v[fi][0]};
            c0 = mfma16(afrag, w1hi[fi][0], c0);
            c0 = mfma16(afrag, w1lo[fi][0], c0);
            f32x4 c1 = {b1v[fi][1], b1v[fi][1], b1v[fi][1], b1v[fi][1]};
            c1 = mfma16(afrag, w1hi[fi][1], c1);
            c1 = mfma16(afrag, w1lo[fi][1], c1);
            short* sHf = (fi == 0) ? sH0 : sH1;
            #pragma unroll
            for (int r4 = 0; r4 < 4; r4++){
                const unsigned p = pack2bf(fmaxf(c0[r4], 0.f), fmaxf(c1[r4], 0.f));
                *(unsigned*)&sHf[(q*4+r4)*40 + 2*l16] = p;   // j=2*l16 (lo), 2*l16+1 (hi)
            }
        }
        asm volatile("s_waitcnt lgkmcnt(0)" ::: "memory");   // wave-internal transpose
        #pragma unroll
        for (int fi = 0; fi < 2; fi++){
            const short* sHf = (fi == 0) ? sH0 : sH1;
            const bf16x8 hf = *(const bf16x8*)(sHf + l16*40 + q*8);
            f32x4 d = {0.f, 0.f, 0.f, 0.f};
            d = mfma16(hf, w2hi[fi], d);
            d = mfma16(hf, w2lo[fi], d);
            #pragma unroll
            for (int r4 = 0; r4 < 4; r4++){
                const float v = d[r4] + b2v[fi];
                if (fi == 0) acc0 = fmaf(v, x0v[r4], acc0);
                else         acc1 = fmaf(v, udv[r4], acc1);
            }
        }
    }

    acc0 += __shfl_down(acc0, 32, 64); acc0 += __shfl_down(acc0, 16, 64);
    acc1 += __shfl_down(acc1, 32, 64); acc1 += __shfl_down(acc1, 16, 64);
    if (lane < 16){ sRed[wv][0][lane] = acc0; sRed[wv][1][lane] = acc1; }
    __syncthreads();
    if (tid < 16){
        sC[0][tid] = sRed[0][0][tid] + sRed[1][0][tid] + sRed[2][0][tid] + sRed[3][0][tid];
        sC[1][tid] = sRed[0][1][tid] + sRed[1][1][tid] + sRed[2][1][tid] + sRed[3][1][tid];
    }
    __syncthreads();
    // per-point readout (was k_readout1) + banked pooled accumulation
    if (tid < C){
        const int g = tid;
        float s = si0b[g];
        #pragma unroll
        for (int f = 0; f < C; f++) s = fmaf(sC[0][f], si0w[g*2*C + f], s);
        #pragma unroll
        for (int f = 0; f < C; f++) s = fmaf(sC[1][f], si0w[g*2*C + C + f], s);
        atomicAdd(&partial[(a & (NBANK-1))*C + g], eluf(s));
    }
    // two-level last-block-done; __syncthreads drains this block's atomics
    __syncthreads();
    if (tid == 0){
        amLast = 0u;
        const unsigned p1 = atomicAdd(&cnt[a & (NBANK-1)], 1u);
        if (p1 == (NP/NBANK) - 1u){
            const unsigned p2 = atomicAdd(&cnt[NBANK], 1u);
            if (p2 == NBANK - 1u) amLast = 1u;
        }
    }
    __syncthreads();
    if (amLast){
        if (tid < C){
            float v = 0.f;
            #pragma unroll
            for (int b = 0; b < NBANK; b++)
                v += __hip_atomic_load(&partial[b*C + tid], __ATOMIC_RELAXED,
                                       __HIP_MEMORY_SCOPE_AGENT);
            sP[tid] = v;
        }
        __syncthreads();
        if (tid < 8){
            float s = fcb[tid];
            #pragma unroll
            for (int g = 0; g < C; g++)
                s = fmaf(sP[g] * (1.0f / (float)NP), fcw[g*8 + tid], s);
            out[tid] = s;
        }
    }
}

extern "C" void kernel_launch(void* const* d_in, const int* in_sizes, int n_in,
                              void* d_out, int out_size, void* d_ws, size_t ws_size,
                              hipStream_t stream)
{
    (void)in_sizes; (void)n_in; (void)out_size; (void)ws_size;
    const float* points   = (const float*)d_in[0];
    const float* l1_W1    = (const float*)d_in[1];
    const float* l1_B1    = (const float*)d_in[2];
    const float* l1_W2    = (const float*)d_in[3];
    const float* l1_B2    = (const float*)d_in[4];
    const float* l1_si0_w = (const float*)d_in[5];
    const float* l1_si0_b = (const float*)d_in[6];
    const float* l1_si1_w = (const float*)d_in[7];
    const float* l1_nl_b  = (const float*)d_in[8];
    const float* l2_W1    = (const float*)d_in[9];
    const float* l2_B1    = (const float*)d_in[10];
    const float* l2_W2    = (const float*)d_in[11];
    const float* l2_B2    = (const float*)d_in[12];
    const float* l2_si0_w = (const float*)d_in[13];
    const float* l2_si0_b = (const float*)d_in[14];
    // d_in[15] l2_si1_w, d_in[16] l2_nl_b: dead code in the reference readout
    const float* fc_w     = (const float*)d_in[17];
    const float* fc_b     = (const float*)d_in[18];

    float* ws       = (float*)d_ws;
    float* x0g      = ws;                    // NP*C
    float* x1s      = x0g + NP*C;            // 3*NP*C (SoA planes)
    float* partial  = x1s + 3*NP*C;          // NBANK*C floats (32 x 64B lines)
    unsigned* cnt   = (unsigned*)(partial + NBANK*C);  // cnt1[NBANK] + cnt2

    k_l1p<<<NP, 256, 0, stream>>>(points, l1_W1, l1_B1, l1_W2, l1_B2,
                                  l1_si0_w, l1_si0_b, l1_si1_w, l1_nl_b,
                                  x0g, x1s, partial, cnt);
    k_l2r<<<NP, 256, 0, stream>>>(points, l2_W1, l2_B1, l2_W2, l2_B2,
                                  x0g, x1s, l2_si0_w, l2_si0_b,
                                  fc_w, fc_b, partial, cnt, (float*)d_out);
}